// Round 10
// baseline (54.432 us; speedup 1.0000x reference)
//
#include <hip/hip_runtime.h>
#include <hip/hip_bf16.h>

// ContrastiveLoss fused kernel for MI355X (gfx950).
//
// Math reduction (T=0.5):
//   f = x / max(||x||, 1e-8)   (rows)
//   s_ij = f_i . f_j
//   den_i = sum_{j: label_j != label_i} exp(2 s_ij)
//   loss  = sum_i [ c_i * log(den_i) - sum_{j same label, j != i} 2 s_ij ]
//           / (sum_i c_i + 1e-5),   c_i = count(label_i) - 1
//
// N=4096, D=512, labels in [0,100).
//
// Round 10: NO LDS PIPELINE. The bf16 matrix (4 MB, fragment-major) fits
// entirely in each XCD's 4 MB L2, and a block's 16 KB slab working set
// fits L1 (shared by its 4 in-phase waves). So B-fragments are read
// directly from global into registers (contiguous 1 KB per wave-op,
// L1/L2-hit), and the main loop has ZERO barriers -- waves independent,
// compiler's counted vmcnt does the pipelining. Rounds 5-9 showed all
// barrier-locked LDS variants (2-phase, quad-buf counted-vmcnt) pin at
// the same ~26 us regardless of work or schedule: the lockstep coupling
// itself was the limiter. Keeps: symmetric 528 tile-pairs, A 2x16
// pinned in 128 VGPRs, tiny LDS for labels + col accumulators.

typedef short short8 __attribute__((ext_vector_type(8)));
typedef float floatx4 __attribute__((ext_vector_type(4)));
typedef unsigned short u16;
typedef unsigned int u32;
typedef unsigned char u8;

#define N_ROWS 4096
#define DIM 512
#define GRPB 16384             // bytes per 16-row fragment group (16*1024)
#define EPS_NORM 1e-8f
#define EPS_DEN 1e-5f
#define TI 128                 // tile size (rows and cols)
#define NT (N_ROWS / TI)       // 32 tiles
#define NPAIR (NT * (NT + 1) / 2)   // 528 blocks
#define NJT 8                  // 8 slabs of 16 j-cols per tile

static __device__ inline u16 f32_to_bf16(float f) {
  u32 u = __float_as_uint(f);
  u32 r = (u + 0x7FFFu + ((u >> 16) & 1u)) >> 16;   // RNE
  return (u16)r;
}

// wave-per-row normalize + bf16 pack, fragment-major store; grid 1024 x 256.
// G layout: group g = row>>4 (16 rows), chunk kt = k>>5 (32 elems), inside a
// 1 KB chunk lane l = kg*16 + (row&15) holds bytes [l*16, l*16+16) =
// elems k = kt*32 + kg*8 .. +8 of its row (the MFMA A/B fragment map).
__global__ void k1_normalize(const float* __restrict__ x,
                             const int* __restrict__ labels,
                             u16* __restrict__ G, u8* __restrict__ lab8,
                             float* __restrict__ den, float* __restrict__ pos,
                             float* __restrict__ acc2) {
  const int row = blockIdx.x * 4 + (threadIdx.x >> 6);
  const int lane = threadIdx.x & 63;
  const float4* src = reinterpret_cast<const float4*>(x + (size_t)row * DIM);
  float4 v0 = src[lane * 2];
  float4 v1 = src[lane * 2 + 1];
  float ss = v0.x*v0.x + v0.y*v0.y + v0.z*v0.z + v0.w*v0.w
           + v1.x*v1.x + v1.y*v1.y + v1.z*v1.z + v1.w*v1.w;
#pragma unroll
  for (int m = 1; m < 64; m <<= 1) ss += __shfl_xor(ss, m, 64);
  float scale = 1.f / fmaxf(sqrtf(ss), EPS_NORM);
  uint4 o;
  o.x = ((u32)f32_to_bf16(v0.y * scale) << 16) | (u32)f32_to_bf16(v0.x * scale);
  o.y = ((u32)f32_to_bf16(v0.w * scale) << 16) | (u32)f32_to_bf16(v0.z * scale);
  o.z = ((u32)f32_to_bf16(v1.y * scale) << 16) | (u32)f32_to_bf16(v1.x * scale);
  o.w = ((u32)f32_to_bf16(v1.w * scale) << 16) | (u32)f32_to_bf16(v1.z * scale);
  char* dst = (char*)G + (size_t)(row >> 4) * GRPB + (lane >> 2) * 1024
            + ((lane & 3) * 16 + (row & 15)) * 16;
  *reinterpret_cast<uint4*>(dst) = o;
  if (lane == 0) { den[row] = 0.f; pos[row] = 0.f; }
  if (lane == 1) lab8[row] = (u8)labels[row];
  if (blockIdx.x == 0 && threadIdx.x == 0) { acc2[0] = 0.f; acc2[1] = 0.f; }
}

// fused sim-GEMM + symmetric per-row/per-col reduction. No B staging:
// B-fragments stream global(L1/L2)->registers; no barriers in main loop.
__global__ __launch_bounds__(256, 2) void k2_fused(
    const u16* __restrict__ G, const u8* __restrict__ lab8,
    float* __restrict__ den, float* __restrict__ pos) {
  __shared__ int labj_sh[TI];
  __shared__ float colden[TI], colpos[TI];

  const char* Gb = (const char*)G;

  // decode pair (ti, tj), ti <= tj, from blockIdx
  int b = blockIdx.x;
  int ti = 0, rem = NT;
  while (b >= rem) { b -= rem; ++ti; --rem; }
  const int tj = ti + b;
  const bool diag = (ti == tj);

  const int tid = threadIdx.x;
  const int wv = tid >> 6;
  const int lane = tid & 63;
  const int l15 = lane & 15;
  const int kg = lane >> 4;               // 0..3

  const int ib = ti * TI;
  const int jb = tj * TI;

  // prologue: labels + col accumulators into (tiny) LDS
  if (tid < TI) {
    labj_sh[tid] = lab8[jb + tid];
    colden[tid] = 0.f;
    colpos[tid] = 0.f;
  }

  // A fragments: 32 rows/wave = 2 fragment groups, K=512, register-resident.
  short8 a[2][16];
#pragma unroll
  for (int s = 0; s < 2; ++s) {
    const char* abase = Gb + (size_t)(ti * 8 + wv * 2 + s) * GRPB + lane * 16;
#pragma unroll
    for (int kt = 0; kt < 16; ++kt)
      a[s][kt] = *reinterpret_cast<const short8*>(abase + kt * 1024);
  }
  // pin A in VGPRs (round-1 pathology: compiler sank loads into the loop)
#pragma unroll
  for (int s = 0; s < 2; ++s)
#pragma unroll
    for (int kt = 0; kt < 16; ++kt)
      asm volatile("" : "+v"(a[s][kt]));

  // C/D layout (verified gfx950): col = lane&15 (j), row = kg*4 + r (i).
  const int i_base = ib + wv * 32 + kg * 4;
  const u32 labp0 = *reinterpret_cast<const u32*>(lab8 + i_base);
  const u32 labp1 = *reinterpret_cast<const u32*>(lab8 + i_base + 16);

  float den_acc[2][4] = {{0.f,0.f,0.f,0.f},{0.f,0.f,0.f,0.f}};
  float pos_acc[2][4] = {{0.f,0.f,0.f,0.f},{0.f,0.f,0.f,0.f}};

  __syncthreads();   // labj_sh / colden / colpos ready

  // main loop: 8 slabs of 16 j-cols; B-fragments straight from global.
  // All 4 waves sweep slabs in the same order -> L1 temporal reuse (slab
  // working set 16 KB, L1 32 KB). No barriers; waves free-run.
#pragma unroll
  for (int t = 0; t < NJT; ++t) {
    const char* bsrc = Gb + (size_t)(tj * 8 + t) * GRPB + lane * 16;
    short8 bfr[16];
#pragma unroll
    for (int kt = 0; kt < 16; ++kt)
      bfr[kt] = *reinterpret_cast<const short8*>(bsrc + kt * 1024);

    floatx4 acc0 = {0.f,0.f,0.f,0.f};
    floatx4 acc1 = {0.f,0.f,0.f,0.f};
#pragma unroll
    for (int kt = 0; kt < 16; ++kt) {
      acc0 = __builtin_amdgcn_mfma_f32_16x16x32_bf16(a[0][kt], bfr[kt], acc0, 0, 0, 0);
      acc1 = __builtin_amdgcn_mfma_f32_16x16x32_bf16(a[1][kt], bfr[kt], acc1, 0, 0, 0);
    }

    const int jrow = jb + t * 16 + l15;
    const int labj = labj_sh[t * 16 + l15];

    float cd = 0.f, cp = 0.f;   // col partials for this 16-j slab
#pragma unroll
    for (int s = 0; s < 2; ++s) {
      floatx4 av = s ? acc1 : acc0;
      const u32 labp = s ? labp1 : labp0;
#pragma unroll
      for (int r = 0; r < 4; ++r) {
        const int labi = (int)((labp >> (8 * r)) & 255u);
        const int irow = i_base + s * 16 + r;
        float s2 = 2.f * av[r];
        float e = __expf(s2);
        bool sm = (labj == labi);
        float dv = sm ? 0.f : e;
        float pv = (sm && (jrow != irow)) ? s2 : 0.f;
        den_acc[s][r] += dv;
        pos_acc[s][r] += pv;
        cd += dv; cp += pv;
      }
    }
    if (!diag) {
      // reduce col partials across the 4 kg groups (lanes sharing l15)
      cd += __shfl_xor(cd, 16, 64); cd += __shfl_xor(cd, 32, 64);
      cp += __shfl_xor(cp, 16, 64); cp += __shfl_xor(cp, 32, 64);
      if (kg == 0) {
        atomicAdd(&colden[t * 16 + l15], cd);
        atomicAdd(&colpos[t * 16 + l15], cp);
      }
    }
  }

  // row path: reduce across the 16 cols (lanes with same kg), 1 atomic/row
#pragma unroll
  for (int s = 0; s < 2; ++s)
#pragma unroll
    for (int r = 0; r < 4; ++r) {
      float dd = den_acc[s][r], p = pos_acc[s][r];
#pragma unroll
      for (int m = 1; m < 16; m <<= 1) {
        dd += __shfl_xor(dd, m, 64);
        p += __shfl_xor(p, m, 64);
      }
      if (l15 == 0) {
        atomicAdd(&den[i_base + s * 16 + r], dd);
        atomicAdd(&pos[i_base + s * 16 + r], p);
      }
    }

  // col path flush (off-diagonal blocks): one atomic per col
  if (!diag) {
    __syncthreads();   // all waves' LDS col atomics done
    if (tid < TI) {
      atomicAdd(&den[jb + tid], colden[tid]);
      atomicAdd(&pos[jb + tid], colpos[tid]);
    }
  }
}

// per-row finalize, 16 blocks x 256 threads; block partial -> global atomics
__global__ void k3a(const float* __restrict__ den, const float* __restrict__ pos,
                    const int* __restrict__ labels, float* __restrict__ acc2) {
  __shared__ int hist[128];
  __shared__ float sn[4], sz[4];
  const int tid = threadIdx.x;
  if (tid < 128) hist[tid] = 0;
  __syncthreads();
  for (int i = tid; i < N_ROWS; i += 256) atomicAdd(&hist[labels[i]], 1);
  __syncthreads();

  const int row = blockIdx.x * 256 + tid;
  int c = hist[labels[row]] - 1;
  float num = (float)c * logf(den[row]) - pos[row];
  float nnz = (float)c;
#pragma unroll
  for (int m = 1; m < 64; m <<= 1) {
    num += __shfl_xor(num, m, 64);
    nnz += __shfl_xor(nnz, m, 64);
  }
  if ((tid & 63) == 0) { sn[tid >> 6] = num; sz[tid >> 6] = nnz; }
  __syncthreads();
  if (tid == 0) {
    atomicAdd(&acc2[0], sn[0] + sn[1] + sn[2] + sn[3]);
    atomicAdd(&acc2[1], sz[0] + sz[1] + sz[2] + sz[3]);
  }
}

__global__ void k3b(const float* __restrict__ acc2, float* __restrict__ out) {
  out[0] = acc2[0] / (acc2[1] + EPS_DEN);
}

extern "C" void kernel_launch(void* const* d_in, const int* in_sizes, int n_in,
                              void* d_out, int out_size, void* d_ws, size_t ws_size,
                              hipStream_t stream) {
  const float* x = (const float*)d_in[0];
  const int* labels = (const int*)d_in[1];

  // ws: G (4MB) | den f32[4096] | pos f32[4096] | lab8 u8[4096] | acc2 f32[2]
  u16* G = (u16*)d_ws;
  float* den = (float*)((char*)d_ws + (size_t)N_ROWS * DIM * 2);
  float* pos = den + N_ROWS;
  u8* lab8 = (u8*)(pos + N_ROWS);
  float* acc2 = (float*)(lab8 + N_ROWS);
  float* out = (float*)d_out;

  hipLaunchKernelGGL(k1_normalize, dim3(N_ROWS / 4), dim3(256), 0, stream,
                     x, labels, G, lab8, den, pos, acc2);
  hipLaunchKernelGGL(k2_fused, dim3(NPAIR), dim3(256), 0, stream,
                     G, lab8, den, pos);
  hipLaunchKernelGGL(k3a, dim3(16), dim3(256), 0, stream,
                     den, pos, labels, acc2);
  hipLaunchKernelGGL(k3b, dim3(1), dim3(1), 0, stream, acc2, out);
}

// Round 11
// 38.177 us; speedup vs baseline: 1.4258x; 1.4258x over previous
//
#include <hip/hip_runtime.h>
#include <hip/hip_bf16.h>
#include <hip/hip_fp8.h>

// ContrastiveLoss fused kernel for MI355X (gfx950).
//
// Math reduction (T=0.5):
//   f = x / max(||x||, 1e-8)   (rows)
//   s_ij = f_i . f_j
//   den_i = sum_{j: label_j != label_i} exp(2 s_ij)
//   loss  = sum_i [ c_i * log(den_i) - sum_{j same label, j != i} 2 s_ij ]
//           / (sum_i c_i + 1e-5),   c_i = count(label_i) - 1
//
// N=4096, D=512, labels in [0,100).
//
// Round 11: FP8 GEMM. Rounds 5-10 analysis: the invariant ~26 us k2 was
// the LDS operand-feed wall -- every bf16 16x16x32 MFMA eats a 1 KB
// ds_read (537 MB total = ~20 us at 85 B/cyc/CU); sync-schedule changes
// (R9) and L1/L2 bypass (R10) both regressed because bytes/FLOP was the
// limiter. fp8 e4m3 (OCP, gfx950) has the SAME lane->(row,k) fragment
// map as bf16 16x16x32 (8 elems/lane), C/D layout dtype-independent:
// only byte widths change. B-fragments 512 B, stored kt-PAIRED so one
// ds_read_b128 feeds 4 MFMAs (2 kt x 2 A-sets) = 64 FLOP/B -> LDS floor
// ~2.6 us, MFMA floor ~4.4 us (symmetric). A = 64 VGPRs -> ~125 total,
// 3-4 waves/SIMD naturally, all 528 blocks co-resident. Sync = the
// best-proven simple 2-phase double-buffer (R7). Accuracy: sigma(s_ij)
// ~1e-3, averages out across 164k loss cells; threshold 0.166.

typedef float floatx4 __attribute__((ext_vector_type(4)));
typedef long lng2 __attribute__((ext_vector_type(2)));
typedef unsigned short u16;
typedef unsigned int u32;
typedef unsigned char u8;

#define N_ROWS 4096
#define DIM 512
#define GRPB 8192              // bytes per 16-row fp8 fragment group (16*512)
#define EPS_NORM 1e-8f
#define EPS_DEN 1e-5f
#define TI 128                 // tile size (rows and cols)
#define NT (N_ROWS / TI)       // 32 tiles
#define NPAIR (NT * (NT + 1) / 2)   // 528 blocks
#define NJT 8                  // 8 slabs of 16 j-rows per tile

static __device__ inline void load_lds16(const char* g, char* l) {
  __builtin_amdgcn_global_load_lds(
      (const __attribute__((address_space(1))) void*)g,
      (__attribute__((address_space(3))) void*)l, 16, 0, 0);
}

// wave-per-row normalize + fp8 pack, fragment-major store; grid 1024 x 256.
// G layout (fp8): group g = row>>4 (16 rows, 8192 B), kt-pair p = kt>>1
// (1024 B), inside: consumer lane l = kg*16 + (row&15) finds its 8-byte
// fragment of kt at byte l*16 + (kt&1)*8  (k = kt*32 + kg*8 + e).
__global__ void k1_normalize(const float* __restrict__ x,
                             const int* __restrict__ labels,
                             u8* __restrict__ G, u8* __restrict__ lab8,
                             float* __restrict__ den, float* __restrict__ pos,
                             float* __restrict__ acc2) {
  const int row = blockIdx.x * 4 + (threadIdx.x >> 6);
  const int lane = threadIdx.x & 63;
  const float4* src = reinterpret_cast<const float4*>(x + (size_t)row * DIM);
  float4 v0 = src[lane * 2];
  float4 v1 = src[lane * 2 + 1];
  float ss = v0.x*v0.x + v0.y*v0.y + v0.z*v0.z + v0.w*v0.w
           + v1.x*v1.x + v1.y*v1.y + v1.z*v1.z + v1.w*v1.w;
#pragma unroll
  for (int m = 1; m < 64; m <<= 1) ss += __shfl_xor(ss, m, 64);
  float scale = 1.f / fmaxf(sqrtf(ss), EPS_NORM);

  u32 lo = ((u32)__hip_fp8_e4m3(v0.x * scale).__x)
         | ((u32)__hip_fp8_e4m3(v0.y * scale).__x << 8)
         | ((u32)__hip_fp8_e4m3(v0.z * scale).__x << 16)
         | ((u32)__hip_fp8_e4m3(v0.w * scale).__x << 24);
  u32 hi = ((u32)__hip_fp8_e4m3(v1.x * scale).__x)
         | ((u32)__hip_fp8_e4m3(v1.y * scale).__x << 8)
         | ((u32)__hip_fp8_e4m3(v1.z * scale).__x << 16)
         | ((u32)__hip_fp8_e4m3(v1.w * scale).__x << 24);
  uint2 o; o.x = lo; o.y = hi;

  const int kt = lane >> 2;           // this lane's 8 elems = k-chunk kt, octet kg
  const int kg = lane & 3;
  char* dst = (char*)G + (size_t)(row >> 4) * GRPB + (kt >> 1) * 1024
            + (kg * 16 + (row & 15)) * 16 + (kt & 1) * 8;
  *reinterpret_cast<uint2*>(dst) = o;

  if (lane == 0) { den[row] = 0.f; pos[row] = 0.f; }
  if (lane == 1) lab8[row] = (u8)labels[row];
  if (blockIdx.x == 0 && threadIdx.x == 0) { acc2[0] = 0.f; acc2[1] = 0.f; }
}

// fused fp8 sim-GEMM + symmetric per-row/per-col reduction.
__global__ __launch_bounds__(256, 2) void k2_fused(
    const u8* __restrict__ G, const u8* __restrict__ lab8,
    float* __restrict__ den, float* __restrict__ pos) {
  // fp8 B slab: 2 buffers x 8 KB (16 rows x 512 k, kt-paired chunks)
  __shared__ u8 Bsh[2 * 8192];
  __shared__ int labj_sh[TI];
  __shared__ float colden[TI], colpos[TI];

  const char* Gb = (const char*)G;
  char* bshb = (char*)Bsh;

  // decode pair (ti, tj), ti <= tj, from blockIdx
  int b = blockIdx.x;
  int ti = 0, rem = NT;
  while (b >= rem) { b -= rem; ++ti; --rem; }
  const int tj = ti + b;
  const bool diag = (ti == tj);

  const int tid = threadIdx.x;
  const int wv = tid >> 6;
  const int lane = tid & 63;
  const int l15 = lane & 15;
  const int kg = lane >> 4;               // 0..3

  const int ib = ti * TI;
  const int jb = tj * TI;

  // stage one 16-row fp8 slab (8 KB = 8 kt-pair chunks); wave wv stages
  // chunks wv*2, wv*2+1. Source AND dest contiguous 1 KB (lane*16).
#define STAGE(bufsel, slab) do {                                            \
    _Pragma("unroll")                                                       \
    for (int i_ = 0; i_ < 2; ++i_) {                                        \
      const int c_ = wv * 2 + i_;                                           \
      load_lds16(Gb + (size_t)(tj * 8 + (slab)) * GRPB + c_ * 1024 + lane * 16, \
                 bshb + (bufsel) * 8192 + c_ * 1024 + lane * 16);           \
    }                                                                       \
  } while (0)

  // prologue: stage slab 0 into buf 0; labels + col accumulators into LDS
  STAGE(0, 0);
  if (tid < TI) {
    labj_sh[tid] = lab8[jb + tid];
    colden[tid] = 0.f;
    colpos[tid] = 0.f;
  }

  // A fragments: 32 rows/wave = 2 fp8 fragment groups, K=512 -> 64 VGPRs.
  long a0[16], a1[16];
  {
    const char* ab0 = Gb + (size_t)(ti * 8 + wv * 2) * GRPB + lane * 16;
    const char* ab1 = ab0 + GRPB;
#pragma unroll
    for (int p = 0; p < 8; ++p) {
      lng2 v0 = *reinterpret_cast<const lng2*>(ab0 + p * 1024);
      lng2 v1 = *reinterpret_cast<const lng2*>(ab1 + p * 1024);
      a0[2 * p] = v0.x; a0[2 * p + 1] = v0.y;
      a1[2 * p] = v1.x; a1[2 * p + 1] = v1.y;
    }
  }
  // pin A in VGPRs (round-1 pathology: compiler sank loads into the loop)
#pragma unroll
  for (int kt = 0; kt < 16; ++kt) {
    asm volatile("" : "+v"(a0[kt]));
    asm volatile("" : "+v"(a1[kt]));
  }

  // C/D layout (verified gfx950, dtype-independent): col = lane&15 (j),
  // row = kg*4 + r (i). lane's 8 output rows: i = i_base + s*16 + r.
  const int i_base = ib + wv * 32 + kg * 4;
  const u32 labp0 = *reinterpret_cast<const u32*>(lab8 + i_base);
  const u32 labp1 = *reinterpret_cast<const u32*>(lab8 + i_base + 16);

  float den_acc[2][4] = {{0.f,0.f,0.f,0.f},{0.f,0.f,0.f,0.f}};
  float pos_acc[2][4] = {{0.f,0.f,0.f,0.f},{0.f,0.f,0.f,0.f}};

  __syncthreads();   // buf0 staged, labels + col accs ready

  for (int t = 0; t < NJT; ++t) {
    const int cur = t & 1;
    if (t + 1 < NJT) STAGE(cur ^ 1, t + 1);

    const int jrow = jb + t * 16 + l15;
    const int labj = labj_sh[t * 16 + l15];

    floatx4 acc0 = {0.f,0.f,0.f,0.f};
    floatx4 acc1 = {0.f,0.f,0.f,0.f};
    const char* bbase = bshb + cur * 8192 + lane * 16;
#pragma unroll
    for (int p = 0; p < 8; ++p) {
      lng2 b2 = *reinterpret_cast<const lng2*>(bbase + p * 1024);
      acc0 = __builtin_amdgcn_mfma_f32_16x16x32_fp8_fp8(a0[2*p],   b2.x, acc0, 0, 0, 0);
      acc1 = __builtin_amdgcn_mfma_f32_16x16x32_fp8_fp8(a1[2*p],   b2.x, acc1, 0, 0, 0);
      acc0 = __builtin_amdgcn_mfma_f32_16x16x32_fp8_fp8(a0[2*p+1], b2.y, acc0, 0, 0, 0);
      acc1 = __builtin_amdgcn_mfma_f32_16x16x32_fp8_fp8(a1[2*p+1], b2.y, acc1, 0, 0, 0);
    }

    float cd = 0.f, cp = 0.f;   // col partials for this 16-j slab
#pragma unroll
    for (int s = 0; s < 2; ++s) {
      floatx4 av = s ? acc1 : acc0;
      const u32 labp = s ? labp1 : labp0;
#pragma unroll
      for (int r = 0; r < 4; ++r) {
        const int labi = (int)((labp >> (8 * r)) & 255u);
        const int irow = i_base + s * 16 + r;
        float s2 = 2.f * av[r];
        float e = __expf(s2);
        bool sm = (labj == labi);
        float dv = sm ? 0.f : e;
        float pv = (sm && (jrow != irow)) ? s2 : 0.f;
        den_acc[s][r] += dv;
        pos_acc[s][r] += pv;
        cd += dv; cp += pv;
      }
    }
    if (!diag) {
      // reduce col partials across the 4 kg groups (lanes sharing l15)
      cd += __shfl_xor(cd, 16, 64); cd += __shfl_xor(cd, 32, 64);
      cp += __shfl_xor(cp, 16, 64); cp += __shfl_xor(cp, 32, 64);
      if (kg == 0) {
        atomicAdd(&colden[t * 16 + l15], cd);
        atomicAdd(&colpos[t * 16 + l15], cp);
      }
    }
    __syncthreads();   // staging for t+1 done; safe to flip buffers
  }

  // row path: reduce across the 16 cols (lanes with same kg), 1 atomic/row
#pragma unroll
  for (int s = 0; s < 2; ++s)
#pragma unroll
    for (int r = 0; r < 4; ++r) {
      float dd = den_acc[s][r], p = pos_acc[s][r];
#pragma unroll
      for (int m = 1; m < 16; m <<= 1) {
        dd += __shfl_xor(dd, m, 64);
        p += __shfl_xor(p, m, 64);
      }
      if (l15 == 0) {
        atomicAdd(&den[i_base + s * 16 + r], dd);
        atomicAdd(&pos[i_base + s * 16 + r], p);
      }
    }

  // col path flush (off-diagonal blocks): one atomic per col
  if (!diag) {
    __syncthreads();   // all waves' LDS col atomics done
    if (tid < TI) {
      atomicAdd(&den[jb + tid], colden[tid]);
      atomicAdd(&pos[jb + tid], colpos[tid]);
    }
  }
#undef STAGE
}

// per-row finalize, 16 blocks x 256 threads; block partial -> global atomics
__global__ void k3a(const float* __restrict__ den, const float* __restrict__ pos,
                    const int* __restrict__ labels, float* __restrict__ acc2) {
  __shared__ int hist[128];
  __shared__ float sn[4], sz[4];
  const int tid = threadIdx.x;
  if (tid < 128) hist[tid] = 0;
  __syncthreads();
  for (int i = tid; i < N_ROWS; i += 256) atomicAdd(&hist[labels[i]], 1);
  __syncthreads();

  const int row = blockIdx.x * 256 + tid;
  int c = hist[labels[row]] - 1;
  float num = (float)c * logf(den[row]) - pos[row];
  float nnz = (float)c;
#pragma unroll
  for (int m = 1; m < 64; m <<= 1) {
    num += __shfl_xor(num, m, 64);
    nnz += __shfl_xor(nnz, m, 64);
  }
  if ((tid & 63) == 0) { sn[tid >> 6] = num; sz[tid >> 6] = nnz; }
  __syncthreads();
  if (tid == 0) {
    atomicAdd(&acc2[0], sn[0] + sn[1] + sn[2] + sn[3]);
    atomicAdd(&acc2[1], sz[0] + sz[1] + sz[2] + sz[3]);
  }
}

__global__ void k3b(const float* __restrict__ acc2, float* __restrict__ out) {
  out[0] = acc2[0] / (acc2[1] + EPS_DEN);
}

extern "C" void kernel_launch(void* const* d_in, const int* in_sizes, int n_in,
                              void* d_out, int out_size, void* d_ws, size_t ws_size,
                              hipStream_t stream) {
  const float* x = (const float*)d_in[0];
  const int* labels = (const int*)d_in[1];

  // ws: G fp8 (2MB) | den f32[4096] | pos f32[4096] | lab8 u8[4096] | acc2
  u8* G = (u8*)d_ws;
  float* den = (float*)((char*)d_ws + (size_t)N_ROWS * DIM);
  float* pos = den + N_ROWS;
  u8* lab8 = (u8*)(pos + N_ROWS);
  float* acc2 = (float*)(lab8 + N_ROWS);
  float* out = (float*)d_out;

  hipLaunchKernelGGL(k1_normalize, dim3(N_ROWS / 4), dim3(256), 0, stream,
                     x, labels, G, lab8, den, pos, acc2);
  hipLaunchKernelGGL(k2_fused, dim3(NPAIR), dim3(256), 0, stream,
                     G, lab8, den, pos);
  hipLaunchKernelGGL(k3a, dim3(16), dim3(256), 0, stream,
                     den, pos, labels, acc2);
  hipLaunchKernelGGL(k3b, dim3(1), dim3(1), 0, stream, acc2, out);
}